// Round 5
// baseline (88.424 us; speedup 1.0000x reference)
//
#include <hip/hip_runtime.h>
#include <hip/hip_bf16.h>

#define BB 1024
#define DD 256
#define NREL 42

typedef __attribute__((ext_vector_type(8))) short short8_t;
typedef __attribute__((ext_vector_type(4))) short short4_t;
typedef __attribute__((ext_vector_type(4))) float f32x4;
typedef __attribute__((ext_vector_type(4))) int   i32x4;

__device__ __forceinline__ unsigned short bf16_of(float f) {
    // round-to-nearest-even f32 -> bf16 (inputs are finite normals)
    unsigned u = __float_as_uint(f);
    return (unsigned short)((u + 0x7FFFu + ((u >> 16) & 1u)) >> 16);
}

__device__ __forceinline__ void gload_lds16(const unsigned short* g, unsigned short* l) {
    __builtin_amdgcn_global_load_lds(
        (const __attribute__((address_space(1))) unsigned int*)g,
        (__attribute__((address_space(3))) unsigned int*)l, 16, 0, 0);
}

// ---------------- K0: x -> bf16 row-major + LDS-tiled transpose -----------------
__global__ __launch_bounds__(256) void cvt_kernel(const float* __restrict__ x,
                                                  unsigned short* __restrict__ xbf,
                                                  unsigned short* __restrict__ xbfT) {
    __shared__ unsigned short t[64][72];
    const int bj = blockIdx.x * 64;
    const int bd = blockIdx.y * 64;
    const int tr = threadIdx.x >> 4;
    const int tc = threadIdx.x & 15;

    #pragma unroll
    for (int rr = 0; rr < 4; ++rr) {
        const int jl = rr * 16 + tr;
        const f32x4 v = *reinterpret_cast<const f32x4*>(&x[(bj + jl) * DD + bd + tc * 4]);
        short4_t h;
        #pragma unroll
        for (int e = 0; e < 4; ++e) h[e] = (short)bf16_of(v[e]);
        *reinterpret_cast<short4_t*>(&xbf[(bj + jl) * DD + bd + tc * 4]) = h;
        *reinterpret_cast<short4_t*>(&t[jl][tc * 4]) = h;
    }
    __syncthreads();
    #pragma unroll
    for (int rr = 0; rr < 4; ++rr) {
        const int dl = rr * 16 + tr;
        short4_t h;
        #pragma unroll
        for (int e = 0; e < 4; ++e) h[e] = (short)t[tc * 4 + e][dl];
        *reinterpret_cast<short4_t*>(&xbfT[(bd + dl) * BB + bj + tc * 4]) = h;
    }
}

// ---------------- K1 (fused): logits GEMM + gather + softmax -> normalized P ----
// 256 blocks x 512 thr (8 waves = 2/SIMD). Block owns 4 rows i; waves 2p,2p+1
// both own row i=blk*4+p, splitting each 32-j tile into two 16-j halves.
// A_i (48x256 bf16) in VGPRs per wave; B tiles (32 j x 256 d, XOR-swizzled)
// double-buffered in LDS via global_load_lds; each wave stages 2 chunks of the
// next tile before computing the current one. Epilogue gathers S[q[i,j], j];
// per-wave full-row softmax writes its half of normalized P.
__global__ __launch_bounds__(512, 1) void attn_kernel(const float* __restrict__ x,
                                                      const int* __restrict__ q,
                                                      const float* __restrict__ R,
                                                      const unsigned short* __restrict__ xbf,
                                                      unsigned short* __restrict__ P) {
    __shared__ unsigned short Bt[2][16384];     // 2 x (32 j x 256 d) bf16, swizzled
    __shared__ float s_attn[4][BB];             // per-i logit row
    __shared__ unsigned short s_qs[4][BB];      // per-i q row (values < 42)

    const int tid  = threadIdx.x;
    const int w    = tid >> 6;       // 0..7
    const int lane = tid & 63;
    const int il   = w >> 1;         // 0..3: which i this wave serves
    const int jh   = w & 1;          // 0/1: which 16-j half
    const int lcol = lane & 15;
    const int g    = lane >> 4;
    const int lk8  = g * 8;
    const int l5   = lane >> 5, l31 = lane & 31;
    const int i    = blockIdx.x * 4 + il;

    // --- stage tile 0 (wave stages 2 chunks; 1 chunk = 2 rows of 512 B) ---
    #pragma unroll
    for (int c0 = 0; c0 < 2; ++c0) {
        const int c = w * 2 + c0;
        const int row = c * 2 + l5;
        const int scol = ((l31 * 16) ^ ((row & 7) << 4)) >> 1;   // pre-swizzled source
        gload_lds16(&xbf[row * DD + scol], &Bt[0][c * 512]);
    }

    // --- q rows -> LDS (u16): 4 rows x 1024 over 512 threads, 8 each ---
    {
        const int r  = tid >> 7;
        const int c8 = (tid & 127) * 8;
        const int qi = blockIdx.x * 4 + r;
        const i32x4 qa = *reinterpret_cast<const i32x4*>(&q[qi * BB + c8]);
        const i32x4 qb = *reinterpret_cast<const i32x4*>(&q[qi * BB + c8 + 4]);
        short4_t sa, sb;
        sa[0] = (short)qa[0]; sa[1] = (short)qa[1]; sa[2] = (short)qa[2]; sa[3] = (short)qa[3];
        sb[0] = (short)qb[0]; sb[1] = (short)qb[1]; sb[2] = (short)qb[2]; sb[3] = (short)qb[3];
        *reinterpret_cast<short4_t*>(&s_qs[r][c8])     = sa;
        *reinterpret_cast<short4_t*>(&s_qs[r][c8 + 4]) = sb;
    }

    // --- A_i fragments in registers: afrag[mt*8+ks] = bf16(R[k][d]*x[i][d]) ---
    short8_t afrag[24];
    #pragma unroll
    for (int ks = 0; ks < 8; ++ks) {
        const int d0 = ks * 32 + lk8;
        const f32x4 x0 = *reinterpret_cast<const f32x4*>(&x[i * DD + d0]);
        const f32x4 x1 = *reinterpret_cast<const f32x4*>(&x[i * DD + d0 + 4]);
        #pragma unroll
        for (int mt = 0; mt < 3; ++mt) {
            const int k = mt * 16 + lcol;
            short8_t v = (short8_t)0;
            if (k < NREL) {
                const f32x4 r0 = *reinterpret_cast<const f32x4*>(&R[k * DD + d0]);
                const f32x4 r1 = *reinterpret_cast<const f32x4*>(&R[k * DD + d0 + 4]);
                #pragma unroll
                for (int e = 0; e < 4; ++e) {
                    v[e]     = (short)bf16_of(r0[e] * x0[e]);
                    v[e + 4] = (short)bf16_of(r1[e] * x1[e]);
                }
            }
            afrag[mt * 8 + ks] = v;
        }
    }

    asm volatile("s_waitcnt vmcnt(0)" ::: "memory");
    __syncthreads();

    const int gsw  = (g * 16) ^ ((lcol & 7) << 4);   // swizzled in-row byte base
    const int brow = jh * 16 + lcol;                 // my B row within the tile

    for (int t = 0; t < 32; ++t) {
        // issue next-tile staging BEFORE compute (L2 latency hides under MFMA)
        if (t < 31) {
            unsigned short* nxt = Bt[(t + 1) & 1];
            const unsigned short* src = &xbf[(t + 1) * 32 * DD];
            #pragma unroll
            for (int c0 = 0; c0 < 2; ++c0) {
                const int c = w * 2 + c0;
                const int row = c * 2 + l5;
                const int scol = ((l31 * 16) ^ ((row & 7) << 4)) >> 1;
                gload_lds16(&src[row * DD + scol], &nxt[c * 512]);
            }
        }

        const char* cur = (const char*)Bt[t & 1];
        f32x4 acc0 = (f32x4)0.0f, acc1 = (f32x4)0.0f, acc2 = (f32x4)0.0f;

        #pragma unroll
        for (int ks = 0; ks < 8; ++ks) {
            const int off = brow * 512 + ((ks * 64) ^ gsw);
            const short8_t b = *reinterpret_cast<const short8_t*>(cur + off);
            acc0 = __builtin_amdgcn_mfma_f32_16x16x32_bf16(afrag[ks],      b, acc0, 0, 0, 0);
            acc1 = __builtin_amdgcn_mfma_f32_16x16x32_bf16(afrag[8 + ks],  b, acc1, 0, 0, 0);
            acc2 = __builtin_amdgcn_mfma_f32_16x16x32_bf16(afrag[16 + ks], b, acc2, 0, 0, 0);
        }

        // Epilogue: my 16 j's; exactly one lane per j holds S[q[i,j], j].
        {
            const int jl = t * 32 + jh * 16 + lcol;
            const int qv = (int)s_qs[il][jl];
            if (((qv >> 2) & 3) == g) {
                const int mt = qv >> 4;                       // 0..2 (qv < 42)
                const f32x4 av = (mt == 0) ? acc0 : (mt == 1) ? acc1 : acc2;
                const float v = (qv & 2) ? ((qv & 1) ? av[3] : av[2])
                                         : ((qv & 1) ? av[1] : av[0]);
                s_attn[il][jl] = v;
            }
        }

        asm volatile("s_waitcnt vmcnt(0)" ::: "memory");   // my 2 staged loads
        __syncthreads();
    }

    // --- softmax: full-row reduce (redundant in wave pair), write own P half ---
    f32x4 v4[4];
    #pragma unroll
    for (int kk = 0; kk < 4; ++kk)
        v4[kk] = *reinterpret_cast<const f32x4*>(&s_attn[il][kk * 256 + lane * 4]);

    float m = -1e30f;
    #pragma unroll
    for (int kk = 0; kk < 4; ++kk)
        m = fmaxf(m, fmaxf(fmaxf(v4[kk][0], v4[kk][1]), fmaxf(v4[kk][2], v4[kk][3])));
    #pragma unroll
    for (int off = 1; off < 64; off <<= 1) m = fmaxf(m, __shfl_xor(m, off));

    float e[16];
    float ssum = 0.f;
    #pragma unroll
    for (int kk = 0; kk < 4; ++kk)
        #pragma unroll
        for (int ee = 0; ee < 4; ++ee) {
            const float t2 = __expf(v4[kk][ee] - m);
            e[kk * 4 + ee] = t2;
            ssum += t2;
        }
    #pragma unroll
    for (int off = 1; off < 64; off <<= 1) ssum += __shfl_xor(ssum, off);
    const float inv = 1.0f / ssum;

    #pragma unroll
    for (int kk2 = 0; kk2 < 2; ++kk2) {
        const int kk = jh * 2 + kk2;
        short4_t p;
        #pragma unroll
        for (int ee = 0; ee < 4; ++ee) p[ee] = (short)bf16_of(e[kk * 4 + ee] * inv);
        *reinterpret_cast<short4_t*>(&P[i * BB + kk * 256 + lane * 4]) = p;
    }
}

// ---------------- K3a: partial out GEMM, split-K z=4 -----------------------------
__global__ __launch_bounds__(256) void out_partial(const unsigned short* __restrict__ P,
                                                   const unsigned short* __restrict__ xbfT,
                                                   float* __restrict__ part) {
    const int tid = threadIdx.x;
    const int wave = tid >> 6, lane = tid & 63;
    const int lcol = lane & 15;
    const int lk8  = (lane >> 4) * 8;
    const int i0 = blockIdx.y * 64 + wave * 16;
    const int d0 = blockIdx.x * 64;
    const int k0 = blockIdx.z * 256;

    f32x4 acc[4];
    #pragma unroll
    for (int nt = 0; nt < 4; ++nt) acc[nt] = (f32x4)0.0f;

    #pragma unroll
    for (int ks = 0; ks < 8; ++ks) {
        const short8_t a = *reinterpret_cast<const short8_t*>(
            &P[(i0 + lcol) * BB + k0 + ks * 32 + lk8]);
        #pragma unroll
        for (int nt = 0; nt < 4; ++nt) {
            const short8_t b = *reinterpret_cast<const short8_t*>(
                &xbfT[(d0 + nt * 16 + lcol) * BB + k0 + ks * 32 + lk8]);
            acc[nt] = __builtin_amdgcn_mfma_f32_16x16x32_bf16(a, b, acc[nt], 0, 0, 0);
        }
    }

    const int rbase = (lane >> 4) * 4;
    float* pz = part + (size_t)blockIdx.z * BB * DD;
    #pragma unroll
    for (int r = 0; r < 4; ++r)
        #pragma unroll
        for (int nt = 0; nt < 4; ++nt)
            pz[(i0 + rbase + r) * DD + d0 + nt * 16 + lcol] = acc[nt][r];
}

// ---------------- K3b: out = sum_z part[z] (P already normalized) ---------------
__global__ __launch_bounds__(256) void out_reduce(const float* __restrict__ part,
                                                  float* __restrict__ out) {
    const int idx = blockIdx.x * DD + threadIdx.x;
    out[idx] = (part[idx] + part[BB * DD + idx]) +
               (part[2 * BB * DD + idx] + part[3 * BB * DD + idx]);
}

// ---------------- launch ---------------------------------------------------------
extern "C" void kernel_launch(void* const* d_in, const int* in_sizes, int n_in,
                              void* d_out, int out_size, void* d_ws, size_t ws_size,
                              hipStream_t stream) {
    (void)in_sizes; (void)n_in; (void)out_size; (void)ws_size;
    const float* x = (const float*)d_in[0];
    // d_in[1] = x_mask (unused), d_in[3] = f (unused)
    const int* q = (const int*)d_in[2];
    const float* R = (const float*)d_in[4];
    float* out = (float*)d_out;

    char* ws = (char*)d_ws;
    unsigned short* xbf  = (unsigned short*)(ws);                  // 512 KB
    unsigned short* xbfT = (unsigned short*)(ws + (512u << 10));   // 512 KB
    unsigned short* P    = (unsigned short*)(ws + (1024u << 10));  // 2 MB
    float*          part = (float*)(ws + (3072u << 10));           // 4 MB (z=4)

    cvt_kernel<<<dim3(16, 4), 256, 0, stream>>>(x, xbf, xbfT);
    attn_kernel<<<dim3(256), 512, 0, stream>>>(x, q, R, xbf, P);
    out_partial<<<dim3(4, 16, 4), 256, 0, stream>>>(P, xbfT, part);
    out_reduce<<<dim3(BB), 256, 0, stream>>>(part, out);
}